// Round 3
// baseline (42.064 us; speedup 1.0000x reference)
//
#include <hip/hip_runtime.h>
#include <hip/hip_bf16.h>
#include <math.h>

#define D     128
#define NT    256            // B*T
#define HD    32
#define LD    32
#define NCH   4              // n's per score block
#define NC    (NT/NCH)       // 64 chunks

static __device__ inline unsigned short f2bf(float f) {
    __hip_bfloat16 b = __float2bfloat16(f);
    return *reinterpret_cast<unsigned short*>(&b);
}

// ---------------------------------------------------------------------------
// Fused kernel: per block = 64x64 (i,j) tile x NCH n's.
//   phase 1: compute pa (i-range rows, +b1) and pb (j-range rows) into LDS
//            directly from z (no HBM roundtrip). W1 rows live in VGPRs.
//   phase 2: scores via lane=i / wave-uniform-j broadcast reads.
//   epilogue: write bf16 chunk-partials in BOTH orientations (coalesced).
// ---------------------------------------------------------------------------
__global__ __launch_bounds__(512) void fused_kernel(
    const float* __restrict__ z, const float* __restrict__ W1,
    const float* __restrict__ b1, const float* __restrict__ W2,
    __hip_bfloat16* __restrict__ Spart, __hip_bfloat16* __restrict__ SpartT)
{
    __shared__ float spa[NCH][64][36];   // pad 36: b128 reads = 8-way = full-BW
    __shared__ float spb[NCH][64][32];   // uniform (broadcast) reads: linear
    __shared__ float sS[64][65];         // transpose buffer; hosts W1 in phase 1

    const int t  = threadIdx.x;
    const int i0 = (blockIdx.x & 1) * 64;
    const int j0 = (blockIdx.x >> 1) * 64;
    const int nc = blockIdx.y;

    // ---- stage W1 into the sS overlay (dead until epilogue) ----
    float (*sW1a)[33] = (float (*)[33])(&sS[0][0]);
    float (*sW1b)[33] = (float (*)[33])(&sS[0][0] + 32 * 33);
    {
        int f = t * 4;                       // 512*4 = 2048 = full W1
        int hh = f >> 6, c = f & 63;
        float4 v = *(const float4*)&W1[f];
        float* dst = (c < 32) ? &sW1a[hh][c] : &sW1b[hh][c - 32];
        dst[0] = v.x; dst[1] = v.y; dst[2] = v.z; dst[3] = v.w;
    }

    float w2r[HD];                           // uniform -> SGPRs
    #pragma unroll
    for (int hh = 0; hh < HD; ++hh) w2r[hh] = W2[hh];

    __syncthreads();

    // ---- phase 1: pa/pb tiles into LDS ----
    {
        const int h = t & 31, slot = t >> 5; // 16 slots x 32 h
        float wa[LD], wb[LD];                // this thread's W1 rows
        #pragma unroll
        for (int k = 0; k < 8; ++k) {
            *(float4*)&wa[k * 4] = *(const float4*)&sW1a[h][k * 4];
            *(float4*)&wb[k * 4] = *(const float4*)&sW1b[h][k * 4];
        }
        const float bias = b1[h];
        #pragma unroll 2
        for (int rr = 0; rr < 16; ++rr) {
            int p = rr * 16 + slot;          // 0..255 = (nn, r)
            int nn = p >> 6, r = p & 63;
            const float* zn = z + (size_t)((nc * NCH + nn) * D) * LD;
            const float* zi = zn + (i0 + r) * LD;
            const float* zj = zn + (j0 + r) * LD;
            float aA = bias, aB = 0.f;
            #pragma unroll
            for (int k = 0; k < 8; ++k) {
                float4 vi = *(const float4*)&zi[k * 4];
                float4 vj = *(const float4*)&zj[k * 4];
                aA = fmaf(vi.x, wa[k*4+0], aA); aA = fmaf(vi.y, wa[k*4+1], aA);
                aA = fmaf(vi.z, wa[k*4+2], aA); aA = fmaf(vi.w, wa[k*4+3], aA);
                aB = fmaf(vj.x, wb[k*4+0], aB); aB = fmaf(vj.y, wb[k*4+1], aB);
                aB = fmaf(vj.z, wb[k*4+2], aB); aB = fmaf(vj.w, wb[k*4+3], aB);
            }
            spa[nn][r][h] = aA;
            spb[nn][r][h] = aB;
        }
    }
    __syncthreads();

    // ---- phase 2: scores ----
    const int lane = t & 63;
    const int jb   = __builtin_amdgcn_readfirstlane((t >> 6) * 8);

    float acc[8];
    #pragma unroll
    for (int jj = 0; jj < 8; ++jj) acc[jj] = 0.f;

    #pragma unroll 1
    for (int nn = 0; nn < NCH; ++nn) {
        float par[HD];                       // this lane's pa row
        #pragma unroll
        for (int k = 0; k < 8; ++k)
            *(float4*)&par[k * 4] = *(const float4*)&spa[nn][lane][k * 4];
        #pragma unroll
        for (int jj = 0; jj < 8; ++jj) {
            float pbv[HD];                   // wave-uniform pb row (broadcast)
            #pragma unroll
            for (int k = 0; k < 8; ++k)
                *(float4*)&pbv[k * 4] = *(const float4*)&spb[nn][jb + jj][k * 4];
            float a = acc[jj];
            #pragma unroll
            for (int h = 0; h < HD; ++h)
                a = fmaf(w2r[h], fmaxf(par[h] + pbv[h], 0.f), a);
            acc[jj] = a;
        }
    }

    // ---- epilogue: bf16 partials, both orientations, coalesced ----
    {   // SpartT[nc][j][i] = S[i][j]; lanes = consecutive i
        __hip_bfloat16* SpT = SpartT + ((size_t)nc * D + j0 + jb) * D + i0;
        #pragma unroll
        for (int jj = 0; jj < 8; ++jj)
            SpT[jj * D + lane] = __float2bfloat16(acc[jj]);
    }
    #pragma unroll
    for (int jj = 0; jj < 8; ++jj)
        sS[lane][jb + jj] = acc[jj];
    __syncthreads();
    {   // Spart[nc][i][j] = S[i][j] via LDS transpose, 16B stores
        int ir = t >> 3;                     // 0..63
        int jc = (t & 7) * 8;                // 0..56
        unsigned int pk[4];
        #pragma unroll
        for (int k = 0; k < 4; ++k) {
            unsigned int lo = f2bf(sS[ir][jc + 2 * k]);
            unsigned int hi = f2bf(sS[ir][jc + 2 * k + 1]);
            pk[k] = (hi << 16) | lo;
        }
        __hip_bfloat16* Sp = Spart + ((size_t)nc * D + i0 + ir) * D + j0 + jc;
        *(uint4*)Sp = *(uint4*)pk;
    }
}

// ---------------------------------------------------------------------------
// Finalize: reduce bf16 partials (both orientations coalesced), antisym,
// sigmoids, Wm. b2 cancels exactly in S - S^T.
// ---------------------------------------------------------------------------
__global__ __launch_bounds__(256) void finalize_kernel(
    const __hip_bfloat16* __restrict__ Spart,
    const __hip_bfloat16* __restrict__ SpartT,
    const float* __restrict__ Wmag, float* __restrict__ out)
{
    const int t = blockIdx.x * 256 + threadIdx.x;   // 0..16383
    const int i = t >> 7, j = t & 127;

    float s = 0.f;
    #pragma unroll 4
    for (int nc = 0; nc < NC; ++nc) {
        float a = __bfloat162float(Spart [(size_t)nc * D * D + t]);  // S[i][j]
        float b = __bfloat162float(SpartT[(size_t)nc * D * D + t]);  // S[j][i]
        s += a - b;
    }
    float av  = s * (1.0f / 256.0f);                // mean over n; TAU = 1
    float dir = 1.0f / (1.0f + __expf(-av));
    float wm  = 0.5f * (Wmag[i * D + j] + Wmag[j * D + i]);
    float A;
    if (i == j) { wm = 0.f; A = 0.f; }
    else        { A = dir / (1.0f + __expf(-wm)); }
    out[t]         = A;
    out[D * D + t] = wm;
}

extern "C" void kernel_launch(void* const* d_in, const int* in_sizes, int n_in,
                              void* d_out, int out_size, void* d_ws, size_t ws_size,
                              hipStream_t stream)
{
    const float* z    = (const float*)d_in[0];   // (4,64,128,32)
    const float* Wmag = (const float*)d_in[1];   // (128,128)
    const float* W1   = (const float*)d_in[2];   // (32,64)
    const float* b1   = (const float*)d_in[3];   // (32,)
    const float* W2   = (const float*)d_in[4];   // (1,32)
    // d_in[5] = b2: cancels in scores - scores^T.

    __hip_bfloat16* Spart  = (__hip_bfloat16*)d_ws;              // 2 MB
    __hip_bfloat16* SpartT = Spart + (size_t)NC * D * D;         // 2 MB
    float* out = (float*)d_out;

    fused_kernel<<<dim3(4, NC), 512, 0, stream>>>(z, W1, b1, W2, Spart, SpartT);
    finalize_kernel<<<(D * D) / 256, 256, 0, stream>>>(Spart, SpartT, Wmag, out);
}